// Round 2
// baseline (378.420 us; speedup 1.0000x reference)
//
#include <hip/hip_runtime.h>

// SE(2) depthwise group convolution, fp32.
// out[b,c,t,y,x] = sum_{o,dy,dx} W[c,t,o,dy,dx] * x[b,c,o,y+dy-2,x+dx-2]
// W[c,t,o,dy,dx] = mask(t,dy,dx) * kernel[c,(o-t)%8, iy(t,dy,dx), ix(t,dy,dx)]
// B=8 C=32 Or=8 H=W=128, kOr=8 kH=kW=5.
//
// Block: one (b,c) x 32x32 spatial tile, all 8 orientations t.
// Thread: (xq, t, ys) -> 4 cols x 8 rows = 32 outputs.
// LDS: 4 input planes (36x36, halo 2) staged twice (o=0..3, then 4..7)
//      = 20736 B + 7168 B weights -> 4 blocks/CU.

#define PLANEF 1296   // 36*36 floats per staged plane

__global__ __launch_bounds__(256, 4)
void se2_dwconv(const float* __restrict__ x, const float* __restrict__ kern,
                float* __restrict__ out) {
    __shared__ float ldsx[4 * PLANEF];   // 20736 B
    __shared__ float ldsw[64 * 28];      // 7168 B, W[t][o][k], k padded 25->28

    const int bid = blockIdx.x;
    const int tx = bid & 3;
    const int ty = (bid >> 2) & 3;
    const int bc = bid >> 4;           // b*32 + c
    const int c  = bc & 31;
    const int b  = bc >> 5;
    const int X0 = tx * 32;
    const int Y0 = ty * 32;
    const int tid = threadIdx.x;

    // ---- build rotated weights for this channel: 64*28 values ----
    for (int e = tid; e < 1792; e += 256) {
        int t   = e / 224;
        int rem = e - t * 224;
        int o   = rem / 28;
        int k   = rem - o * 28;
        float w = 0.0f;
        if (k < 25) {
            int dy = k / 5;
            int dx = k - dy * 5;
            int tp = (o - t) & 7;
            float ang = 6.2831855f * (float)t / 8.0f;
            float ca = cosf(ang), sa = sinf(ang);
            float xx = (float)dx - 2.0f;
            float yy = (float)dy - 2.0f;
            float ysf = sa * xx + ca * yy + 2.0f;
            float xsf = ca * xx - sa * yy + 2.0f;
            int iy = (int)rintf(ysf);   // round-nearest-even == jnp.round
            int ix = (int)rintf(xsf);
            if (iy >= 0 && iy < 5 && ix >= 0 && ix < 5)
                w = kern[((c * 8 + tp) * 5 + iy) * 5 + ix];
        }
        ldsw[e] = w;
    }

    const int xq = tid & 7;           // 8 x-quads -> 32 columns
    const int t  = (tid >> 3) & 7;    // orientation
    const int ys = tid >> 6;          // 0..3 row-groups of 8
    const int x0 = xq * 4;
    const int y0 = ys * 8;

    const float* xbase = x + (size_t)(b * 32 + c) * 8 * 16384;

    float acc[32];
#pragma unroll
    for (int i = 0; i < 32; ++i) acc[i] = 0.0f;

#pragma unroll 1
    for (int s = 0; s < 2; ++s) {
        if (s) __syncthreads();   // previous compute must finish before restage

        // ---- stage planes s*4 .. s*4+3 as float4 chunks ----
#pragma unroll 1
        for (int e = tid; e < 1296; e += 256) {
            int oo  = e / 324;
            int rem = e - oo * 324;
            int r   = rem / 9;
            int cx  = rem - r * 9;
            int gy  = Y0 - 2 + r;
            int gx0 = X0 - 2 + cx * 4;
            const float* src = xbase + ((s * 4 + oo) * 16384 + gy * 128 + gx0);
            float4 v;
            if (gy >= 0 && gy < 128 && gx0 >= 0 && gx0 <= 124) {
                float2 a  = *reinterpret_cast<const float2*>(src);      // 8B aligned
                float2 b2 = *reinterpret_cast<const float2*>(src + 2);
                v = make_float4(a.x, a.y, b2.x, b2.y);
            } else {
                bool gyok = (gy >= 0 && gy < 128);
                v.x = (gyok && gx0 + 0 >= 0 && gx0 + 0 < 128) ? src[0] : 0.0f;
                v.y = (gyok && gx0 + 1 >= 0 && gx0 + 1 < 128) ? src[1] : 0.0f;
                v.z = (gyok && gx0 + 2 >= 0 && gx0 + 2 < 128) ? src[2] : 0.0f;
                v.w = (gyok && gx0 + 3 >= 0 && gx0 + 3 < 128) ? src[3] : 0.0f;
            }
            *reinterpret_cast<float4*>(&ldsx[oo * PLANEF + r * 36 + cx * 4]) = v;
        }
        __syncthreads();

        // ---- compute 4 orientations' contribution ----
#pragma unroll 1
        for (int oo = 0; oo < 4; ++oo) {
            const float4* wp4 =
                reinterpret_cast<const float4*>(&ldsw[(t * 8 + s * 4 + oo) * 28]);
            float w[28];
#pragma unroll
            for (int j = 0; j < 7; ++j) {
                float4 q = wp4[j];
                w[4 * j + 0] = q.x; w[4 * j + 1] = q.y;
                w[4 * j + 2] = q.z; w[4 * j + 3] = q.w;
            }
            const float* px = &ldsx[oo * PLANEF + y0 * 36 + x0];
#pragma unroll
            for (int rr = 0; rr < 12; ++rr) {
                float4 va = *reinterpret_cast<const float4*>(px + rr * 36);     // 16B aligned
                float4 vb = *reinterpret_cast<const float4*>(px + rr * 36 + 4);
                float v[8] = {va.x, va.y, va.z, va.w, vb.x, vb.y, vb.z, vb.w};
#pragma unroll
                for (int dy = 0; dy < 5; ++dy) {
                    const int yrel = rr - dy;   // compile-time after unroll
                    if (yrel >= 0 && yrel < 8) {
#pragma unroll
                        for (int dx = 0; dx < 5; ++dx) {
                            float wv = w[dy * 5 + dx];
                            acc[yrel * 4 + 0] += wv * v[dx + 0];
                            acc[yrel * 4 + 1] += wv * v[dx + 1];
                            acc[yrel * 4 + 2] += wv * v[dx + 2];
                            acc[yrel * 4 + 3] += wv * v[dx + 3];
                        }
                    }
                }
            }
        }
    }

    // ---- write 8 rows x 4 cols as float4 ----
    const size_t obase = ((size_t)(b * 32 + c) * 8 + t) * 16384;
#pragma unroll
    for (int y = 0; y < 8; ++y) {
        size_t off = obase + (size_t)(Y0 + y0 + y) * 128 + (X0 + x0);
        *reinterpret_cast<float4*>(out + off) =
            make_float4(acc[y * 4 + 0], acc[y * 4 + 1], acc[y * 4 + 2], acc[y * 4 + 3]);
    }
}

extern "C" void kernel_launch(void* const* d_in, const int* in_sizes, int n_in,
                              void* d_out, int out_size, void* d_ws, size_t ws_size,
                              hipStream_t stream) {
    const float* x    = (const float*)d_in[0];
    const float* kern = (const float*)d_in[1];
    float* out = (float*)d_out;
    // grid: 8 b * 32 c * 4 ty * 4 tx = 4096 blocks
    dim3 grid(4096), block(256);
    se2_dwconv<<<grid, block, 0, stream>>>(x, kern, out);
}

// Round 3
// 85.927 us; speedup vs baseline: 4.4040x; 4.4040x over previous
//
#include <hip/hip_runtime.h>

// SE(2) depthwise group conv via bf16 MFMA.
// Per (b,c): out[8t][16384 pix] = W[8 x 200] @ im2col(x)[200 x 16384]
//   K = 200 = 25 taps x 8 orientations (o innermost), padded to 224 (28 taps).
//   M = 16 (t rows 0-7 real, 8-15 zero), N = pixels in groups of 16.
// mfma_f32_16x16x32_bf16:
//   A lane l: row=l&15 (t), k=8*(l>>4)+j  -> tap=cc*4+(l>>4), o=j
//   B lane l: col=l&15 (pix), k=8*(l>>4)+j
//   C lane l: col=l&15 (pix), row=(l>>4)*4+reg (t); lanes>=32 hold zero rows.
// LDS x-tile: [36 r][36 col][8 o] bf16 (o contiguous => B-frag = 1 ds_read_b128).

typedef short bf16x8 __attribute__((ext_vector_type(8)));
typedef float f32x4 __attribute__((ext_vector_type(4)));

#define LW 36

__device__ inline unsigned short f2bf(float f) {   // RNE f32->bf16
    unsigned int u = __float_as_uint(f);
    u += 0x7fffu + ((u >> 16) & 1u);
    return (unsigned short)(u >> 16);
}

__global__ __launch_bounds__(256)
void se2_mfma(const float* __restrict__ x, const float* __restrict__ kern,
              float* __restrict__ out) {
    __shared__ __align__(16) unsigned short ldsx[LW * LW * 8];  // 20736 B
    __shared__ __align__(16) unsigned short ldsw[16 * 28 * 8];  // 7168 B

    const int bid = blockIdx.x;
    const int tx = bid & 3, ty = (bid >> 2) & 3;
    const int bc = bid >> 4;          // b*32 + c
    const int c  = bc & 31;
    const int X0 = tx * 32, Y0 = ty * 32;
    const int tid = threadIdx.x;

    // ---- rotated weights -> ldsw[t][tap][o], bf16; t>=8 or tap>=25 => 0 ----
    for (int e = tid; e < 3584; e += 256) {
        int o   = e & 7;
        int tt  = e >> 3;            // t*28 + tap
        int t   = tt / 28;
        int tap = tt - t * 28;
        float w = 0.0f;
        if (t < 8 && tap < 25) {
            int dy = tap / 5, dx = tap - 5 * (tap / 5);
            int tp = (o - t) & 7;
            float ang = 6.2831855f * (float)t / 8.0f;
            float ca = cosf(ang), sa = sinf(ang);
            float xx = (float)dx - 2.0f, yy = (float)dy - 2.0f;
            int iy = (int)rintf(sa * xx + ca * yy + 2.0f);
            int ix = (int)rintf(ca * xx - sa * yy + 2.0f);
            if (iy >= 0 && iy < 5 && ix >= 0 && ix < 5)
                w = kern[((c * 8 + tp) * 5 + iy) * 5 + ix];
        }
        ldsw[e] = f2bf(w);
    }

    // ---- stage x tile: ldsx[r][col][o] bf16, one b128 write per position ----
    const float* xbase = x + (size_t)bc * 8 * 16384;
    for (int e = tid; e < LW * LW; e += 256) {
        int r = e / LW, col = e - r * LW;
        int gy = Y0 - 2 + r, gx = X0 - 2 + col;
        unsigned int w4x = 0, w4y = 0, w4z = 0, w4w = 0;
        if (gy >= 0 && gy < 128 && gx >= 0 && gx < 128) {
            const float* src = xbase + gy * 128 + gx;
            float a0 = src[0 * 16384], a1 = src[1 * 16384];
            float a2 = src[2 * 16384], a3 = src[3 * 16384];
            float a4 = src[4 * 16384], a5 = src[5 * 16384];
            float a6 = src[6 * 16384], a7 = src[7 * 16384];
            w4x = (unsigned)f2bf(a0) | ((unsigned)f2bf(a1) << 16);
            w4y = (unsigned)f2bf(a2) | ((unsigned)f2bf(a3) << 16);
            w4z = (unsigned)f2bf(a4) | ((unsigned)f2bf(a5) << 16);
            w4w = (unsigned)f2bf(a6) | ((unsigned)f2bf(a7) << 16);
        }
        *reinterpret_cast<uint4*>(&ldsx[e * 8]) = make_uint4(w4x, w4y, w4z, w4w);
    }
    __syncthreads();

    // ---- per-lane constants ----
    const int lane  = tid & 63;
    const int wv    = tid >> 6;        // wave id: rows y = wv*8 .. wv*8+7
    const int g     = lane >> 4;       // k-group
    const int col16 = lane & 15;       // pixel-within-16 / A row t

    int    tapoff[7];
    bf16x8 afrag[7];
#pragma unroll
    for (int cc = 0; cc < 7; ++cc) {
        int tap  = cc * 4 + g;
        int tapc = tap < 25 ? tap : 24;           // B addr for padded K (A row is 0)
        int dy = tapc / 5, dx = tapc - 5 * (tapc / 5);
        tapoff[cc] = (dy * LW + dx) * 8;          // in shorts
        afrag[cc] = *reinterpret_cast<const bf16x8*>(&ldsw[(col16 * 28 + tap) * 8]);
    }

    const size_t obase = (size_t)bc * 8 * 16384;
    float* outp = out + obase + (size_t)(g * 4) * 16384 + X0 + col16;

    // ---- main: 16 col-tiles (8 y-rows x 2 x-halves) per wave ----
#pragma unroll 1
    for (int ct = 0; ct < 16; ++ct) {
        int y  = wv * 8 + (ct >> 1);
        int xh = ct & 1;
        int baseS = (y * LW + xh * 16 + col16) * 8;
        f32x4 acc = {0.f, 0.f, 0.f, 0.f};
#pragma unroll
        for (int cc = 0; cc < 7; ++cc) {
            bf16x8 bf = *reinterpret_cast<const bf16x8*>(&ldsx[baseS + tapoff[cc]]);
            acc = __builtin_amdgcn_mfma_f32_16x16x32_bf16(afrag[cc], bf, acc, 0, 0, 0);
        }
        if (lane < 32) {
            float* po = outp + (size_t)(Y0 + y) * 128 + xh * 16;
            po[0 * 16384] = acc[0];
            po[1 * 16384] = acc[1];
            po[2 * 16384] = acc[2];
            po[3 * 16384] = acc[3];
        }
    }
}

extern "C" void kernel_launch(void* const* d_in, const int* in_sizes, int n_in,
                              void* d_out, int out_size, void* d_ws, size_t ws_size,
                              hipStream_t stream) {
    const float* x    = (const float*)d_in[0];
    const float* kern = (const float*)d_in[1];
    float* out = (float*)d_out;
    dim3 grid(4096), block(256);   // 8b * 32c * 4ty * 4tx
    se2_mfma<<<grid, block, 0, stream>>>(x, kern, out);
}

// Round 4
// 81.893 us; speedup vs baseline: 4.6209x; 1.0493x over previous
//
#include <hip/hip_runtime.h>

// SE(2) depthwise group conv via bf16 MFMA (fp32 accum).
// Per (b,c): out[8t][16384 pix] = W[8 x 200] @ im2col(x)[200 x 16384]
//   K = 28 taps x 8 orientations (o innermost), taps 25-27 zero-padded.
// mfma_f32_16x16x32_bf16 with A = x-frag (rows = 16 pixels), B = w-frag
// (cols = t, 8 real + 8 zero):
//   A lane l: row = l&15 (pixel), k = 8*(l>>4)+j
//   B lane l: col = l&15 (t),     k = 8*(l>>4)+j
//   D lane l: col = l&15 (t), row = (l>>4)*4+reg (pixel) -> float4 store.
// LDS x-tile: [36 r][40 col][8 o] bf16, col 0 <-> gx = X0-4 (16B-aligned quads).

typedef short bf16x8 __attribute__((ext_vector_type(8)));
typedef float f32x4 __attribute__((ext_vector_type(4)));

#define LWC 40
#define LWR 36

__device__ inline unsigned short f2bf(float f) {   // RNE f32->bf16
    unsigned int u = __float_as_uint(f);
    u += 0x7fffu + ((u >> 16) & 1u);
    return (unsigned short)(u >> 16);
}
__device__ inline unsigned pk2(float a, float b) {
    return (unsigned)f2bf(a) | ((unsigned)f2bf(b) << 16);
}

// cos/sin of 2*pi*t/8, f32. NN-rounding margins >=0.035 -> table-vs-libm safe.
__device__ __constant__ float CA8[8] = {1.0f, 0.70710678f, 0.0f, -0.70710678f,
                                        -1.0f, -0.70710678f, 0.0f, 0.70710678f};
__device__ __constant__ float SA8[8] = {0.0f, 0.70710678f, 1.0f, 0.70710678f,
                                        0.0f, -0.70710678f, -1.0f, -0.70710678f};

__global__ __launch_bounds__(256)
void se2_mfma(const float* __restrict__ x, const float* __restrict__ kern,
              float* __restrict__ out) {
    __shared__ __align__(16) unsigned short ldsx[LWR * LWC * 8];  // 23040 B
    __shared__ __align__(16) unsigned short ldsw[8 * 28 * 8];     //  3584 B

    const int bid = blockIdx.x;
    const int tx = bid & 3, ty = (bid >> 2) & 3;
    const int bc = bid >> 4;          // b*32 + c
    const int c  = bc & 31;
    const int X0 = tx * 32, Y0 = ty * 32;
    const int tid = threadIdx.x;

    // ---- rotated weights -> ldsw[t][tap][o] bf16 (t<8; tap>=25 zero) ----
    for (int e = tid; e < 1792; e += 256) {
        int t   = e / 224;
        int rem = e - t * 224;
        int tap = rem >> 3;
        int o   = rem & 7;
        float w = 0.0f;
        if (tap < 25) {
            int dy = tap / 5, dx = tap - 5 * (tap / 5);
            float ca = CA8[t], sa = SA8[t];
            float xx = (float)dx - 2.0f, yy = (float)dy - 2.0f;
            int iy = (int)rintf(sa * xx + ca * yy + 2.0f);  // RNE == jnp.round
            int ix = (int)rintf(ca * xx - sa * yy + 2.0f);
            if (iy >= 0 && iy < 5 && ix >= 0 && ix < 5) {
                int tp = (o - t) & 7;
                w = kern[(c * 8 + tp) * 25 + iy * 5 + ix];
            }
        }
        ldsw[e] = f2bf(w);
    }

    // ---- stage x tile: 36 rows x 10 aligned quads, o-interleaved bf16 ----
    const float* xbase = x + (size_t)bc * 131072;
    for (int e = tid; e < 360; e += 256) {
        int r  = e / 10, cq = e - r * 10;
        int gy = Y0 - 2 + r;
        int gx0 = X0 - 4 + cq * 4;     // 16B-aligned; in-range all-or-nothing
        float4 p[8];
        if (gy >= 0 && gy < 128 && gx0 >= 0 && gx0 <= 124) {
            const float* src = xbase + gy * 128 + gx0;
#pragma unroll
            for (int o = 0; o < 8; ++o)
                p[o] = *reinterpret_cast<const float4*>(src + o * 16384);
        } else {
#pragma unroll
            for (int o = 0; o < 8; ++o) p[o] = make_float4(0.f, 0.f, 0.f, 0.f);
        }
        unsigned short* dst = &ldsx[(r * LWC + cq * 4) * 8];
        *reinterpret_cast<uint4*>(dst + 0) =
            make_uint4(pk2(p[0].x, p[1].x), pk2(p[2].x, p[3].x),
                       pk2(p[4].x, p[5].x), pk2(p[6].x, p[7].x));
        *reinterpret_cast<uint4*>(dst + 8) =
            make_uint4(pk2(p[0].y, p[1].y), pk2(p[2].y, p[3].y),
                       pk2(p[4].y, p[5].y), pk2(p[6].y, p[7].y));
        *reinterpret_cast<uint4*>(dst + 16) =
            make_uint4(pk2(p[0].z, p[1].z), pk2(p[2].z, p[3].z),
                       pk2(p[4].z, p[5].z), pk2(p[6].z, p[7].z));
        *reinterpret_cast<uint4*>(dst + 24) =
            make_uint4(pk2(p[0].w, p[1].w), pk2(p[2].w, p[3].w),
                       pk2(p[4].w, p[5].w), pk2(p[6].w, p[7].w));
    }
    __syncthreads();

    // ---- per-lane constants ----
    const int lane  = tid & 63;
    const int wv    = tid >> 6;        // wave: rows y = wv*8 .. wv*8+7
    const int g     = lane >> 4;       // k-group
    const int col16 = lane & 15;

    bf16x8 wfrag[7];
    int    tapoff[7];
    const bf16x8 zfrag = {0, 0, 0, 0, 0, 0, 0, 0};
#pragma unroll
    for (int cc = 0; cc < 7; ++cc) {
        int tap  = cc * 4 + g;
        int tapc = tap < 25 ? tap : 24;           // safe addr for padded K
        int dy = tapc / 5, dx = tapc - 5 * (tapc / 5);
        tapoff[cc] = (dy * LWC + dx) * 8;         // in shorts
        wfrag[cc] = (col16 < 8)
            ? *reinterpret_cast<const bf16x8*>(&ldsw[(col16 * 28 + tap) * 8])
            : zfrag;
    }

    float* outl = out + (size_t)bc * 131072 + (size_t)col16 * 16384 +
                  (size_t)Y0 * 128 + X0 + g * 4;

    // ---- main: 16 col-tiles (8 y-rows x 2 x-halves) per wave ----
#pragma unroll 1
    for (int ct = 0; ct < 16; ++ct) {
        int y  = wv * 8 + (ct >> 1);
        int xh = ct & 1;
        int baseS = (y * LWC + 2 + xh * 16 + col16) * 8;
        f32x4 acc = {0.f, 0.f, 0.f, 0.f};
#pragma unroll
        for (int cc = 0; cc < 7; ++cc) {
            bf16x8 xf = *reinterpret_cast<const bf16x8*>(&ldsx[baseS + tapoff[cc]]);
            acc = __builtin_amdgcn_mfma_f32_16x16x32_bf16(xf, wfrag[cc], acc, 0, 0, 0);
        }
        if (col16 < 8)
            *reinterpret_cast<float4*>(outl + (size_t)y * 128 + xh * 16) =
                make_float4(acc[0], acc[1], acc[2], acc[3]);
    }
}

extern "C" void kernel_launch(void* const* d_in, const int* in_sizes, int n_in,
                              void* d_out, int out_size, void* d_ws, size_t ws_size,
                              hipStream_t stream) {
    const float* x    = (const float*)d_in[0];
    const float* kern = (const float*)d_in[1];
    float* out = (float*)d_out;
    dim3 grid(4096), block(256);   // 8b * 32c * 4ty * 4tx
    se2_mfma<<<grid, block, 0, stream>>>(x, kern, out);
}

// Round 5
// 58.357 us; speedup vs baseline: 6.4846x; 1.4033x over previous
//
#include <hip/hip_runtime.h>

// SE(2) depthwise group conv via bf16 MFMA (fp32 accum).
// Per (b,c): out[8t][16384 pix] = W[8 x 200] @ im2col(x)[200 x 16384]
//   K = 28 taps x 8 orientations (o innermost), taps 25-27 zero weights.
// mfma_f32_16x16x32_bf16, A = x-frag (rows = 16 pixels), B = w-frag (cols = t):
//   A lane l: row = l&15 (pixel), k = 8*(l>>4)+j
//   B lane l: col = l&15 (t; 8 real + 8 zero), k = 8*(l>>4)+j
//   D lane l: col = l&15 (t), row = (l>>4)*4+reg (pixel) -> float4 store.
// LDS x-tile: [36 r][36 c][8 o] bf16; (r,c) chunk = 16 B; col 0 <-> gx = X0-2.
// Staging: thread-per-chunk, contiguous ds_write_b128 (conflict-free).
// Grid: XCD-chunked swizzle so the 16 tiles of one (b,c) share an XCD's L2.

typedef short bf16x8 __attribute__((ext_vector_type(8)));
typedef float f32x4 __attribute__((ext_vector_type(4)));

__device__ inline unsigned short f2bf(float f) {   // RNE f32->bf16
    unsigned int u = __float_as_uint(f);
    u += 0x7fffu + ((u >> 16) & 1u);
    return (unsigned short)(u >> 16);
}
__device__ inline unsigned pk2(float a, float b) {
    return (unsigned)f2bf(a) | ((unsigned)f2bf(b) << 16);
}

// cos/sin of 2*pi*t/8, f32. NN-rounding margins >=0.035 -> table-vs-libm safe.
__device__ __constant__ float CA8[8] = {1.0f, 0.70710678f, 0.0f, -0.70710678f,
                                        -1.0f, -0.70710678f, 0.0f, 0.70710678f};
__device__ __constant__ float SA8[8] = {0.0f, 0.70710678f, 1.0f, 0.70710678f,
                                        0.0f, -0.70710678f, -1.0f, -0.70710678f};

__global__ __launch_bounds__(256)
void se2_mfma(const float* __restrict__ x, const float* __restrict__ kern,
              float* __restrict__ out) {
    __shared__ __align__(16) unsigned short ldsx[36 * 36 * 8];  // 20736 B
    __shared__ __align__(16) unsigned short ldsw[8 * 28 * 8];   //  3584 B

    // XCD-chunked bijective swizzle: 4096 blocks, 8 XCDs, 512 per XCD.
    const int bid = (blockIdx.x & 7) * 512 + (blockIdx.x >> 3);
    const int tx = bid & 3, ty = (bid >> 2) & 3;
    const int bc = bid >> 4;          // b*32 + c
    const int c  = bc & 31;
    const int X0 = tx * 32, Y0 = ty * 32;
    const int tid = threadIdx.x;

    // ---- rotated weights -> ldsw[t][tap][o] bf16 (tap>=25 => 0) ----
    for (int e = tid; e < 1792; e += 256) {
        int t   = e / 224;
        int rem = e - t * 224;
        int tap = rem >> 3;
        int o   = rem & 7;
        float w = 0.0f;
        if (tap < 25) {
            int dy = tap / 5, dx = tap - 5 * (tap / 5);
            float ca = CA8[t], sa = SA8[t];
            float xx = (float)dx - 2.0f, yy = (float)dy - 2.0f;
            int iy = (int)rintf(sa * xx + ca * yy + 2.0f);  // RNE == jnp.round
            int ix = (int)rintf(ca * xx - sa * yy + 2.0f);
            if (iy >= 0 && iy < 5 && ix >= 0 && ix < 5) {
                int tp = (o - t) & 7;
                w = kern[(c * 8 + tp) * 25 + iy * 5 + ix];
            }
        }
        ldsw[e] = f2bf(w);
    }

    // ---- stage x tile: thread e -> chunk (r,c), 8 coalesced dword loads,
    //      one contiguous ds_write_b128 (conflict-free) ----
    const float* xbase = x + (size_t)bc * 131072;
    for (int e = tid; e < 1296; e += 256) {
        int r  = e / 36, cc2 = e - r * 36;
        int gy = Y0 - 2 + r, gx = X0 - 2 + cc2;
        float v[8];
        if (gy >= 0 && gy < 128 && gx >= 0 && gx < 128) {
            const float* src = xbase + gy * 128 + gx;
#pragma unroll
            for (int o = 0; o < 8; ++o) v[o] = src[o * 16384];
        } else {
#pragma unroll
            for (int o = 0; o < 8; ++o) v[o] = 0.0f;
        }
        *reinterpret_cast<uint4*>(&ldsx[e * 8]) =
            make_uint4(pk2(v[0], v[1]), pk2(v[2], v[3]),
                       pk2(v[4], v[5]), pk2(v[6], v[7]));
    }
    __syncthreads();

    // ---- per-lane constants ----
    const int lane  = tid & 63;
    const int wv    = tid >> 6;        // wave: rows y = wv*8 .. wv*8+7
    const int g     = lane >> 4;       // k-group
    const int col16 = lane & 15;

    bf16x8 wfrag[7];
    int    tapoff[7];
    const bf16x8 zfrag = {0, 0, 0, 0, 0, 0, 0, 0};
#pragma unroll
    for (int cc = 0; cc < 7; ++cc) {
        int tap  = cc * 4 + g;
        int tapc = tap < 25 ? tap : 24;           // padded K reads broadcast addr
        int dy = tapc / 5, dx = tapc - 5 * (tapc / 5);
        tapoff[cc] = (dy * 36 + dx) * 8;          // in shorts
        wfrag[cc] = (col16 < 8)
            ? *reinterpret_cast<const bf16x8*>(&ldsw[(col16 * 28 + tap) * 8])
            : zfrag;
    }

    float* outl = out + (size_t)bc * 131072 + (size_t)col16 * 16384 +
                  (size_t)Y0 * 128 + X0 + g * 4;

    // ---- main: 16 col-tiles (8 y-rows x 2 x-halves) per wave ----
#pragma unroll 1
    for (int ct = 0; ct < 16; ++ct) {
        int y  = wv * 8 + (ct >> 1);
        int xh = ct & 1;
        int baseS = (y * 36 + xh * 16 + col16) * 8;
        f32x4 acc = {0.f, 0.f, 0.f, 0.f};
#pragma unroll
        for (int cc = 0; cc < 7; ++cc) {
            bf16x8 xf = *reinterpret_cast<const bf16x8*>(&ldsx[baseS + tapoff[cc]]);
            acc = __builtin_amdgcn_mfma_f32_16x16x32_bf16(xf, wfrag[cc], acc, 0, 0, 0);
        }
        if (col16 < 8)
            *reinterpret_cast<float4*>(outl + (size_t)y * 128 + xh * 16) =
                make_float4(acc[0], acc[1], acc[2], acc[3]);
    }
}

extern "C" void kernel_launch(void* const* d_in, const int* in_sizes, int n_in,
                              void* d_out, int out_size, void* d_ws, size_t ws_size,
                              hipStream_t stream) {
    const float* x    = (const float*)d_in[0];
    const float* kern = (const float*)d_in[1];
    float* out = (float*)d_out;
    dim3 grid(4096), block(256);   // 8b * 32c * 4ty * 4tx (swizzled in-kernel)
    se2_mfma<<<grid, block, 0, stream>>>(x, kern, out);
}